// Round 1
// baseline (213.044 us; speedup 1.0000x reference)
//
#include <hip/hip_runtime.h>
#include <stdint.h>

// SupConLossWithPrototype on MI355X.
// Key algebraic reduction: only NOVEL columns of S=F F^T/T are ever used.
//   novel i: needs sumS = sum_{j novel, j!=i} S_ij, sumE = sum_{j novel, j!=i} exp(S_ij)
//   base  i: needs sumE over novel j only
// So: compact novel rows (perm gather), do M x Nn x K bf16 MFMA flash-style
// (row-sums only, S never materialized), subtract the diagonal for novel i
// in a final per-row pass. Proto terms stay fp32 (tiny M x B x K).

#define M_TOT 8192
#define K_DIM 128
#define B_PRO 100
#define INV_T 5.0f      // 1/TEMP
#define CJ    512       // novel-column chunk per block
#define LDA   136       // LDS row stride in bf16 (128 + 8 pad -> 2-way bank alias only, free)

typedef __attribute__((ext_vector_type(8))) short  short8;   // 8 bf16 = 4 VGPR (MFMA A/B frag)
typedef __attribute__((ext_vector_type(4))) float  floatx4;  // MFMA C/D frag

__device__ __forceinline__ float bf2f(unsigned short u) {
    union { unsigned int i; float f; } v; v.i = ((unsigned int)u) << 16; return v.f;
}
__device__ __forceinline__ unsigned short f2bf(float x) {   // RNE
    union { float f; unsigned int i; } v; v.f = x;
    return (unsigned short)((v.i + 0x7fffu + ((v.i >> 16) & 1u)) >> 16);
}

// ---------------------------------------------------------------- k_proto
// One block per row i (128 thr, t<100 active): P[i,b] fp32 dots, Psum,
// exp-Psum, P[i,label], base/novel flag, and append novel i to perm list.
__global__ void k_proto(const float* __restrict__ feat, const int* __restrict__ labels,
                        const float* __restrict__ protos, const int* __restrict__ plabels,
                        float* __restrict__ Psum, float* __restrict__ expPsum,
                        float* __restrict__ PLab, int* __restrict__ nf,
                        int* __restrict__ perm, int* __restrict__ count) {
    const int i = blockIdx.x;
    const int t = threadIdx.x;
    __shared__ float sh[128];
    __shared__ int   baseFlag;
    __shared__ float shPLab;
    if (t == 0) baseFlag = 0;
    __syncthreads();

    const int lbl = labels[i];
    float Pv = 0.f;
    if (t < B_PRO) {
        const float* fr = feat + (size_t)i * K_DIM;
        const float* pr = protos + (size_t)t * K_DIM;
        float d = 0.f;
        #pragma unroll 8
        for (int k = 0; k < K_DIM; ++k) d += fr[k] * pr[k];
        Pv = d * INV_T;
        if (plabels[t] == lbl) baseFlag = 1;  // benign same-value race
    }
    __syncthreads();
    const int isBase = baseFlag;

    // reduce sum(P)
    sh[t] = (t < B_PRO) ? Pv : 0.f;
    __syncthreads();
    for (int s = 64; s > 0; s >>= 1) { if (t < s) sh[t] += sh[t + s]; __syncthreads(); }
    const float ps = sh[0];
    __syncthreads();
    // reduce sum(exp(P))
    sh[t] = (t < B_PRO) ? __expf(Pv) : 0.f;
    __syncthreads();
    for (int s = 64; s > 0; s >>= 1) { if (t < s) sh[t] += sh[t + s]; __syncthreads(); }
    const float es = sh[0];

    // P[i, safe_label] (clamp for safety; only used when base)
    int col = 0;
    if (isBase) { col = lbl < 0 ? 0 : (lbl >= B_PRO ? B_PRO - 1 : lbl); }
    if (t == col) shPLab = Pv;
    __syncthreads();

    if (t == 0) {
        Psum[i] = ps; expPsum[i] = es; PLab[i] = shPLab;
        const int nov = isBase ? 0 : 1;
        nf[i] = nov;
        if (nov) { int pos = atomicAdd(count, 1); perm[pos] = i; }
    }
}

// ---------------------------------------------------------------- k_convert
// fp32 -> bf16 (RNE), float4-in / ushort4-out.
__global__ void k_convert(const float* __restrict__ feat, unsigned short* __restrict__ Fb) {
    const int idx = blockIdx.x * blockDim.x + threadIdx.x;   // one float4
    float4 v = ((const float4*)feat)[idx];
    ushort4 o = make_ushort4(f2bf(v.x), f2bf(v.y), f2bf(v.z), f2bf(v.w));
    ((ushort4*)Fb)[idx] = o;
}

// ---------------------------------------------------------------- k_gather
// Compact novel rows: Fn[jj] = Fb[perm[jj]], 16B chunks.
__global__ void k_gather(const unsigned short* __restrict__ Fb, const int* __restrict__ perm,
                         const int* __restrict__ count, unsigned short* __restrict__ Fn) {
    const int idx = blockIdx.x * blockDim.x + threadIdx.x;   // one 16B chunk
    const int row = idx >> 4, g = idx & 15;
    if (row < *count) {
        const int src = perm[row];
        ((uint4*)Fn)[row * 16 + g] = ((const uint4*)Fb)[(size_t)src * 16 + g];
    }
}

// ---------------------------------------------------------------- k_main
// Block = 256 thr (4 waves), 64 rows, one CJ-wide novel-column chunk.
// All waves share the A rows (a_frags preloaded to regs, 64 VGPR); per
// 64-col j-step each wave owns a 16-col slice -> 4 b128 LDS reads per
// 16 MFMAs. Row-sums accumulate per-lane, butterfly over the 16-lane
// column group at the end, LDS-combine across waves, one atomicAdd/row.
__global__ __launch_bounds__(256) void k_main(const unsigned short* __restrict__ Fb,
                                              const unsigned short* __restrict__ Fn,
                                              const int* __restrict__ count,
                                              float* __restrict__ rowSumExp,
                                              float* __restrict__ rowSumS) {
    __shared__ unsigned short Alds[64 * LDA];
    __shared__ unsigned short Blds[64 * LDA];
    __shared__ float Rs[4][64];
    __shared__ float Re[4][64];

    const int Nn = *count;
    const int chunkStart = blockIdx.x * CJ;
    if (chunkStart >= Nn) return;                    // uniform exit, no barrier hazard
    const int chunkEnd = min(Nn, chunkStart + CJ);
    const int rowBase = blockIdx.y * 64;

    const int tid = threadIdx.x;
    const int wave = tid >> 6, lane = tid & 63;
    const int quad = lane >> 4, c = lane & 15;

    // stage A (64 rows x 128 bf16)
    for (int idx = tid; idx < 1024; idx += 256) {
        const int r = idx >> 4, g = idx & 15;
        *(uint4*)&Alds[r * LDA + g * 8] = ((const uint4*)Fb)[(size_t)(rowBase + r) * 16 + g];
    }
    __syncthreads();

    // preload A fragments: a_frag[mt][ks] covers rows mt*16+c, k = ks*32+quad*8..+7
    short8 a_frag[4][4];
    #pragma unroll
    for (int mt = 0; mt < 4; ++mt)
        #pragma unroll
        for (int ks = 0; ks < 4; ++ks)
            a_frag[mt][ks] = *(const short8*)&Alds[(mt * 16 + c) * LDA + ks * 32 + quad * 8];

    float accS[4][4], accE[4][4];
    #pragma unroll
    for (int mt = 0; mt < 4; ++mt)
        #pragma unroll
        for (int r = 0; r < 4; ++r) { accS[mt][r] = 0.f; accE[mt][r] = 0.f; }

    for (int js = chunkStart; js < chunkEnd; js += 64) {
        __syncthreads();   // protect Blds from previous iteration's readers
        for (int idx = tid; idx < 1024; idx += 256) {
            const int r = idx >> 4, g = idx & 15;
            const int jj = js + r;
            uint4 v = make_uint4(0, 0, 0, 0);
            if (jj < chunkEnd) v = ((const uint4*)Fn)[(size_t)jj * 16 + g];
            *(uint4*)&Blds[r * LDA + g * 8] = v;
        }
        __syncthreads();

        floatx4 D[4];
        #pragma unroll
        for (int mt = 0; mt < 4; ++mt) D[mt] = (floatx4){0.f, 0.f, 0.f, 0.f};

        #pragma unroll
        for (int ks = 0; ks < 4; ++ks) {
            const short8 b = *(const short8*)&Blds[(wave * 16 + c) * LDA + ks * 32 + quad * 8];
            D[0] = __builtin_amdgcn_mfma_f32_16x16x32_bf16(a_frag[0][ks], b, D[0], 0, 0, 0);
            D[1] = __builtin_amdgcn_mfma_f32_16x16x32_bf16(a_frag[1][ks], b, D[1], 0, 0, 0);
            D[2] = __builtin_amdgcn_mfma_f32_16x16x32_bf16(a_frag[2][ks], b, D[2], 0, 0, 0);
            D[3] = __builtin_amdgcn_mfma_f32_16x16x32_bf16(a_frag[3][ks], b, D[3], 0, 0, 0);
        }

        // lane's column for this j-step (one col, 16 rows)
        const int col = js + wave * 16 + c;
        if (col < chunkEnd) {
            #pragma unroll
            for (int mt = 0; mt < 4; ++mt)
                #pragma unroll
                for (int r = 0; r < 4; ++r) {
                    const float v = D[mt][r];        // raw dot; scale by 5 deferred
                    accS[mt][r] += v;
                    accE[mt][r] += __expf(v * INV_T);
                }
        }
    }

    // reduce over the 16-lane column group (butterfly stays inside group)
    #pragma unroll
    for (int mt = 0; mt < 4; ++mt)
        #pragma unroll
        for (int r = 0; r < 4; ++r) {
            float s = accS[mt][r], e = accE[mt][r];
            for (int off = 1; off < 16; off <<= 1) {
                s += __shfl_xor(s, off);
                e += __shfl_xor(e, off);
            }
            if (c == 0) {
                const int row = mt * 16 + quad * 4 + r;
                Rs[wave][row] = s; Re[wave][row] = e;
            }
        }
    __syncthreads();
    if (tid < 64) {
        const float s = Rs[0][tid] + Rs[1][tid] + Rs[2][tid] + Rs[3][tid];
        atomicAdd(&rowSumS[rowBase + tid], s);
    } else if (tid < 128) {
        const int r0 = tid - 64;
        const float e = Re[0][r0] + Re[1][r0] + Re[2][r0] + Re[3][r0];
        atomicAdd(&rowSumExp[rowBase + r0], e);
    }
}

// ---------------------------------------------------------------- k_final
// Per-row loss; novel rows subtract their own diagonal (recomputed from the
// same bf16 values -> matches MFMA to ~1e-4, negligible vs threshold).
__global__ void k_final(const int* __restrict__ labels, const int* __restrict__ nf,
                        const float* __restrict__ rowSumExp, const float* __restrict__ rowSumS,
                        const float* __restrict__ Psum, const float* __restrict__ expPsum,
                        const float* __restrict__ PLab, const unsigned short* __restrict__ Fb,
                        const int* __restrict__ count, float* __restrict__ out) {
    const int i = blockIdx.x * blockDim.x + threadIdx.x;
    float contrib;
    if (nf[i]) {
        const unsigned short* fr = Fb + (size_t)i * K_DIM;
        float d = 0.f;
        #pragma unroll 8
        for (int k = 0; k < K_DIM; ++k) { const float x = bf2f(fr[k]); d += x * x; }
        const float Sii = INV_T * d;
        const float eii = __expf(Sii);
        const float cnt = (float)(*count - 1);
        const float denom = (rowSumExp[i] - eii) + Psum[i];   // + RAW proto-logit sum (faithful)
        const float num = INV_T * (rowSumS[i] - d) - logf(denom) * cnt;
        const float sc = cnt > 0.f ? cnt : 1.f;
        contrib = -(num / sc);
    } else {
        contrib = -(PLab[i] - logf(rowSumExp[i] + expPsum[i]));
    }
    __shared__ float sh[256];
    sh[threadIdx.x] = contrib;
    __syncthreads();
    for (int s = 128; s > 0; s >>= 1) {
        if (threadIdx.x < s) sh[threadIdx.x] += sh[threadIdx.x + s];
        __syncthreads();
    }
    if (threadIdx.x == 0) atomicAdd(out, sh[0] * (1.0f / (float)M_TOT));
}

// ---------------------------------------------------------------- launch
extern "C" void kernel_launch(void* const* d_in, const int* in_sizes, int n_in,
                              void* d_out, int out_size, void* d_ws, size_t ws_size,
                              hipStream_t stream) {
    const float* feat    = (const float*)d_in[0];
    const int*   labels  = (const int*)d_in[1];
    const float* protos  = (const float*)d_in[2];
    const int*   plabels = (const int*)d_in[3];
    float* out = (float*)d_out;

    char* ws = (char*)d_ws;
    // [0,16)      int count (zeroed)
    // [16,32784)  rowSumExp[8192] (zeroed)
    // [32784,65552) rowSumS[8192] (zeroed)
    int*   count     = (int*)ws;
    float* rowSumExp = (float*)(ws + 16);
    float* rowSumS   = (float*)(ws + 16 + 32768);
    float* Psum      = (float*)(ws + 65552);
    float* expPsum   = (float*)(ws + 98320);
    float* PLab      = (float*)(ws + 131088);
    int*   nf        = (int*)(ws + 163856);
    int*   perm      = (int*)(ws + 196624);
    unsigned short* Fb = (unsigned short*)(ws + 229392);            // 16B aligned
    unsigned short* Fn = (unsigned short*)(ws + 229392 + 2097152);  // 16B aligned

    hipMemsetAsync(d_ws, 0, 65552, stream);
    hipMemsetAsync(d_out, 0, sizeof(float), stream);

    k_proto<<<M_TOT, 128, 0, stream>>>(feat, labels, protos, plabels,
                                       Psum, expPsum, PLab, nf, perm, count);
    k_convert<<<(M_TOT * K_DIM / 4) / 256, 256, 0, stream>>>(feat, Fb);
    k_gather<<<(M_TOT * 16) / 256, 256, 0, stream>>>(Fb, perm, count, Fn);
    dim3 gmain(M_TOT / CJ, M_TOT / 64);   // (16 chunks, 128 row-blocks); ~half exit early
    k_main<<<gmain, 256, 0, stream>>>(Fb, Fn, count, rowSumExp, rowSumS);
    k_final<<<M_TOT / 256, 256, 0, stream>>>(labels, nf, rowSumExp, rowSumS,
                                             Psum, expPsum, PLab, Fb, count, out);
}

// Round 2
// 152.313 us; speedup vs baseline: 1.3987x; 1.3987x over previous
//
#include <hip/hip_runtime.h>
#include <stdint.h>

// SupConLossWithPrototype on MI355X.
// Algebraic reduction: only NOVEL columns of S=F F^T/T are ever used.
//   novel i: sumS = sum_{j novel, j!=i} S_ij, sumE = sum_{j novel, j!=i} exp(S_ij)
//   base  i: sumE over novel j only
// Pipeline: k_proto2 (P terms via LDS-tiled bf16 dots + fp32->bf16 convert +
// diag norms + novel perm list) -> k_gather (compact novel rows) ->
// k_main (M x Nn x K bf16 MFMA flash-style row sums) -> k_final (elementwise).

#define M_TOT 8192
#define K_DIM 128
#define B_PRO 100
#define INV_T 5.0f      // 1/TEMP
#define CJ    512       // novel-column chunk per k_main block
#define LDA   136       // k_main LDS row stride in bf16 (128+8 pad)
#define PS    136       // k_proto2 proto LDS stride (shorts); 136*2B=68 words, %32=4 -> 2-way only
#define FS    136       // k_proto2 feat LDS stride (shorts)

typedef __attribute__((ext_vector_type(8))) short  short8;   // 8 bf16 = 4 VGPR (MFMA A/B frag)
typedef __attribute__((ext_vector_type(4))) float  floatx4;  // MFMA C/D frag

__device__ __forceinline__ float bf2f(unsigned short u) {
    union { unsigned int i; float f; } v; v.i = ((unsigned int)u) << 16; return v.f;
}
__device__ __forceinline__ unsigned short f2bf(float x) {   // RNE
    union { float f; unsigned int i; } v; v.f = x;
    return (unsigned short)((v.i + 0x7fffu + ((v.i >> 16) & 1u)) >> 16);
}
__device__ __forceinline__ float lo_bf(unsigned int u) {
    union { unsigned int i; float f; } v; v.i = u << 16; return v.f;
}
__device__ __forceinline__ float hi_bf(unsigned int u) {
    union { unsigned int i; float f; } v; v.i = u & 0xffff0000u; return v.f;
}

// ---------------------------------------------------------------- k_proto2
// 512 blocks x 256 thr; 16 feature rows per block. Stages protos (bf16,
// zero-padded to 128 rows) + feat rows (bf16) in LDS; also emits Fb (bf16
// features, global) and diag[i] = sum_k bf16(f_ik)^2. Thread (rp=t>>4,
// pq=t&15) computes 8 proto dots for row rp; per-row Psum/expPsum/PLab/base
// reduced via 16-lane shuffle butterfly. One atomic per novel row -> perm.
__global__ __launch_bounds__(256) void k_proto2(
        const float* __restrict__ feat, const int* __restrict__ labels,
        const float* __restrict__ protos, const int* __restrict__ plabels,
        float* __restrict__ Psum, float* __restrict__ expPsum,
        float* __restrict__ PLab, int* __restrict__ nf,
        int* __restrict__ perm, int* __restrict__ count,
        unsigned short* __restrict__ Fb, float* __restrict__ diag) {
    __shared__ unsigned short protoB[128 * PS];
    __shared__ unsigned short featB[16 * FS];
    __shared__ int labL[16];
    __shared__ int plabL[B_PRO];

    const int tid = threadIdx.x;
    const int rowBase = blockIdx.x * 16;

    if (tid < B_PRO) plabL[tid] = plabels[tid];
    if (tid >= 128 && tid < 144) labL[tid - 128] = labels[rowBase + tid - 128];

    // stage protos -> bf16 LDS (rows >= 100 zeroed). thread: row tid>>1, half tid&1.
    {
        const int pr = tid >> 1, h = tid & 1;
        unsigned short* dst = &protoB[pr * PS + h * 64];
        if (pr < B_PRO) {
            const float* src = protos + pr * K_DIM + h * 64;
            #pragma unroll
            for (int j = 0; j < 16; ++j) {
                float4 v = ((const float4*)src)[j];
                *(ushort4*)&dst[j * 4] = make_ushort4(f2bf(v.x), f2bf(v.y), f2bf(v.z), f2bf(v.w));
            }
        } else {
            #pragma unroll
            for (int j = 0; j < 16; ++j) *(ushort4*)&dst[j * 4] = make_ushort4(0, 0, 0, 0);
        }
    }

    // stage feat row -> bf16 LDS + Fb global + diag partial.
    // thread: row tid>>4, seg tid&15, elems seg*8..seg*8+7 (coalesced).
    float dpart = 0.f;
    {
        const int row = tid >> 4, seg = tid & 15;
        const float* src = feat + (size_t)(rowBase + row) * K_DIM + seg * 8;
        float4 a = ((const float4*)src)[0];
        float4 b = ((const float4*)src)[1];
        ushort4 o0 = make_ushort4(f2bf(a.x), f2bf(a.y), f2bf(a.z), f2bf(a.w));
        ushort4 o1 = make_ushort4(f2bf(b.x), f2bf(b.y), f2bf(b.z), f2bf(b.w));
        *(ushort4*)&featB[row * FS + seg * 8]     = o0;
        *(ushort4*)&featB[row * FS + seg * 8 + 4] = o1;
        unsigned short* fbd = Fb + (size_t)(rowBase + row) * K_DIM + seg * 8;
        *(ushort4*)&fbd[0] = o0;
        *(ushort4*)&fbd[4] = o1;
        float v;
        v = bf2f(o0.x); dpart += v * v;  v = bf2f(o0.y); dpart += v * v;
        v = bf2f(o0.z); dpart += v * v;  v = bf2f(o0.w); dpart += v * v;
        v = bf2f(o1.x); dpart += v * v;  v = bf2f(o1.y); dpart += v * v;
        v = bf2f(o1.z); dpart += v * v;  v = bf2f(o1.w); dpart += v * v;
    }
    // diag butterfly over the 16-lane seg group
    for (int off = 1; off < 16; off <<= 1) dpart += __shfl_xor(dpart, off);
    if ((tid & 15) == 0) diag[rowBase + (tid >> 4)] = dpart;

    __syncthreads();

    const int rp = tid >> 4, pq = tid & 15;
    float acc[8];
    #pragma unroll
    for (int s = 0; s < 8; ++s) acc[s] = 0.f;

    const unsigned short* fRow = &featB[rp * FS];
    for (int kc = 0; kc < K_DIM; kc += 16) {
        uint4 q0 = *(const uint4*)&fRow[kc];
        uint4 q1 = *(const uint4*)&fRow[kc + 8];
        float f[16];
        f[0]=lo_bf(q0.x); f[1]=hi_bf(q0.x); f[2]=lo_bf(q0.y); f[3]=hi_bf(q0.y);
        f[4]=lo_bf(q0.z); f[5]=hi_bf(q0.z); f[6]=lo_bf(q0.w); f[7]=hi_bf(q0.w);
        f[8]=lo_bf(q1.x); f[9]=hi_bf(q1.x); f[10]=lo_bf(q1.y); f[11]=hi_bf(q1.y);
        f[12]=lo_bf(q1.z); f[13]=hi_bf(q1.z); f[14]=lo_bf(q1.w); f[15]=hi_bf(q1.w);
        #pragma unroll
        for (int s = 0; s < 8; ++s) {
            const int b = pq + (s & 3) * 16 + (s >> 2) * 64;
            const unsigned short* pRow = &protoB[b * PS];
            uint4 p0 = *(const uint4*)&pRow[kc];
            uint4 p1 = *(const uint4*)&pRow[kc + 8];
            float a = acc[s];
            a += lo_bf(p0.x)*f[0];  a += hi_bf(p0.x)*f[1];
            a += lo_bf(p0.y)*f[2];  a += hi_bf(p0.y)*f[3];
            a += lo_bf(p0.z)*f[4];  a += hi_bf(p0.z)*f[5];
            a += lo_bf(p0.w)*f[6];  a += hi_bf(p0.w)*f[7];
            a += lo_bf(p1.x)*f[8];  a += hi_bf(p1.x)*f[9];
            a += lo_bf(p1.y)*f[10]; a += hi_bf(p1.y)*f[11];
            a += lo_bf(p1.z)*f[12]; a += hi_bf(p1.z)*f[13];
            a += lo_bf(p1.w)*f[14]; a += hi_bf(p1.w)*f[15];
            acc[s] = a;
        }
    }

    // per-row epilogue: mask b<100, reduce over the 16 pq lanes
    const int lbl = labL[rp];
    float psum = 0.f, esum = 0.f, plab = 0.f, flg = 0.f;
    #pragma unroll
    for (int s = 0; s < 8; ++s) {
        const int b = pq + (s & 3) * 16 + (s >> 2) * 64;
        if (b < B_PRO) {
            const float Pv = acc[s] * INV_T;
            psum += Pv;
            esum += __expf(Pv);
            if (b == lbl) plab += Pv;
            if (plabL[b] == lbl) flg = 1.f;
        }
    }
    for (int off = 1; off < 16; off <<= 1) {
        psum += __shfl_xor(psum, off);
        esum += __shfl_xor(esum, off);
        plab += __shfl_xor(plab, off);
        flg  += __shfl_xor(flg,  off);
    }
    if (pq == 0) {
        const int i = rowBase + rp;
        Psum[i] = psum; expPsum[i] = esum; PLab[i] = plab;
        const int nov = (flg > 0.f) ? 0 : 1;
        nf[i] = nov;
        if (nov) { int pos = atomicAdd(count, 1); perm[pos] = i; }
    }
}

// ---------------------------------------------------------------- k_gather
// Compact novel rows: Fn[jj] = Fb[perm[jj]], 16B chunks.
__global__ void k_gather(const unsigned short* __restrict__ Fb, const int* __restrict__ perm,
                         const int* __restrict__ count, unsigned short* __restrict__ Fn) {
    const int idx = blockIdx.x * blockDim.x + threadIdx.x;   // one 16B chunk
    const int row = idx >> 4, g = idx & 15;
    if (row < *count) {
        const int src = perm[row];
        ((uint4*)Fn)[row * 16 + g] = ((const uint4*)Fb)[(size_t)src * 16 + g];
    }
}

// ---------------------------------------------------------------- k_main
// Block = 256 thr (4 waves), 64 rows, one CJ-wide novel-column chunk.
// All waves share the A rows (a_frags preloaded to regs); per 64-col j-step
// each wave owns a 16-col slice -> 4 b128 LDS reads per 16 MFMAs. Row-sums
// accumulate per-lane, butterfly over the 16-lane column group at the end,
// LDS-combine across waves, one atomicAdd/row.
__global__ __launch_bounds__(256) void k_main(const unsigned short* __restrict__ Fb,
                                              const unsigned short* __restrict__ Fn,
                                              const int* __restrict__ count,
                                              float* __restrict__ rowSumExp,
                                              float* __restrict__ rowSumS) {
    __shared__ unsigned short Alds[64 * LDA];
    __shared__ unsigned short Blds[64 * LDA];
    __shared__ float Rs[4][64];
    __shared__ float Re[4][64];

    const int Nn = *count;
    const int chunkStart = blockIdx.x * CJ;
    if (chunkStart >= Nn) return;                    // uniform exit, no barrier hazard
    const int chunkEnd = min(Nn, chunkStart + CJ);
    const int rowBase = blockIdx.y * 64;

    const int tid = threadIdx.x;
    const int wave = tid >> 6, lane = tid & 63;
    const int quad = lane >> 4, c = lane & 15;

    // stage A (64 rows x 128 bf16)
    for (int idx = tid; idx < 1024; idx += 256) {
        const int r = idx >> 4, g = idx & 15;
        *(uint4*)&Alds[r * LDA + g * 8] = ((const uint4*)Fb)[(size_t)(rowBase + r) * 16 + g];
    }
    __syncthreads();

    // preload A fragments: a_frag[mt][ks] covers rows mt*16+c, k = ks*32+quad*8..+7
    short8 a_frag[4][4];
    #pragma unroll
    for (int mt = 0; mt < 4; ++mt)
        #pragma unroll
        for (int ks = 0; ks < 4; ++ks)
            a_frag[mt][ks] = *(const short8*)&Alds[(mt * 16 + c) * LDA + ks * 32 + quad * 8];

    float accS[4][4], accE[4][4];
    #pragma unroll
    for (int mt = 0; mt < 4; ++mt)
        #pragma unroll
        for (int r = 0; r < 4; ++r) { accS[mt][r] = 0.f; accE[mt][r] = 0.f; }

    for (int js = chunkStart; js < chunkEnd; js += 64) {
        __syncthreads();   // protect Blds from previous iteration's readers
        for (int idx = tid; idx < 1024; idx += 256) {
            const int r = idx >> 4, g = idx & 15;
            const int jj = js + r;
            uint4 v = make_uint4(0, 0, 0, 0);
            if (jj < chunkEnd) v = ((const uint4*)Fn)[(size_t)jj * 16 + g];
            *(uint4*)&Blds[r * LDA + g * 8] = v;
        }
        __syncthreads();

        floatx4 D[4];
        #pragma unroll
        for (int mt = 0; mt < 4; ++mt) D[mt] = (floatx4){0.f, 0.f, 0.f, 0.f};

        #pragma unroll
        for (int ks = 0; ks < 4; ++ks) {
            const short8 b = *(const short8*)&Blds[(wave * 16 + c) * LDA + ks * 32 + quad * 8];
            D[0] = __builtin_amdgcn_mfma_f32_16x16x32_bf16(a_frag[0][ks], b, D[0], 0, 0, 0);
            D[1] = __builtin_amdgcn_mfma_f32_16x16x32_bf16(a_frag[1][ks], b, D[1], 0, 0, 0);
            D[2] = __builtin_amdgcn_mfma_f32_16x16x32_bf16(a_frag[2][ks], b, D[2], 0, 0, 0);
            D[3] = __builtin_amdgcn_mfma_f32_16x16x32_bf16(a_frag[3][ks], b, D[3], 0, 0, 0);
        }

        // lane's column for this j-step (one col, 16 rows)
        const int col = js + wave * 16 + c;
        if (col < chunkEnd) {
            #pragma unroll
            for (int mt = 0; mt < 4; ++mt)
                #pragma unroll
                for (int r = 0; r < 4; ++r) {
                    const float v = D[mt][r];        // raw dot; scale by 5 deferred
                    accS[mt][r] += v;
                    accE[mt][r] += __expf(v * INV_T);
                }
        }
    }

    // reduce over the 16-lane column group (butterfly stays inside group)
    #pragma unroll
    for (int mt = 0; mt < 4; ++mt)
        #pragma unroll
        for (int r = 0; r < 4; ++r) {
            float s = accS[mt][r], e = accE[mt][r];
            for (int off = 1; off < 16; off <<= 1) {
                s += __shfl_xor(s, off);
                e += __shfl_xor(e, off);
            }
            if (c == 0) {
                const int row = mt * 16 + quad * 4 + r;
                Rs[wave][row] = s; Re[wave][row] = e;
            }
        }
    __syncthreads();
    if (tid < 64) {
        const float s = Rs[0][tid] + Rs[1][tid] + Rs[2][tid] + Rs[3][tid];
        atomicAdd(&rowSumS[rowBase + tid], s);
    } else if (tid < 128) {
        const int r0 = tid - 64;
        const float e = Re[0][r0] + Re[1][r0] + Re[2][r0] + Re[3][r0];
        atomicAdd(&rowSumExp[rowBase + r0], e);
    }
}

// ---------------------------------------------------------------- k_final
// Purely elementwise now: diag precomputed in k_proto2 (matches the bf16
// values the MFMA consumed).
__global__ void k_final(const int* __restrict__ nf,
                        const float* __restrict__ rowSumExp, const float* __restrict__ rowSumS,
                        const float* __restrict__ Psum, const float* __restrict__ expPsum,
                        const float* __restrict__ PLab, const float* __restrict__ diag,
                        const int* __restrict__ count, float* __restrict__ out) {
    const int i = blockIdx.x * blockDim.x + threadIdx.x;
    float contrib;
    if (nf[i]) {
        const float d = diag[i];
        const float eii = __expf(INV_T * d);
        const float cnt = (float)(*count - 1);
        const float denom = (rowSumExp[i] - eii) + Psum[i];   // + RAW proto-logit sum (faithful)
        const float num = INV_T * (rowSumS[i] - d) - logf(denom) * cnt;
        const float sc = cnt > 0.f ? cnt : 1.f;
        contrib = -(num / sc);
    } else {
        contrib = -(PLab[i] - logf(rowSumExp[i] + expPsum[i]));
    }
    __shared__ float sh[256];
    sh[threadIdx.x] = contrib;
    __syncthreads();
    for (int s = 128; s > 0; s >>= 1) {
        if (threadIdx.x < s) sh[threadIdx.x] += sh[threadIdx.x + s];
        __syncthreads();
    }
    if (threadIdx.x == 0) atomicAdd(out, sh[0] * (1.0f / (float)M_TOT));
}

// ---------------------------------------------------------------- launch
extern "C" void kernel_launch(void* const* d_in, const int* in_sizes, int n_in,
                              void* d_out, int out_size, void* d_ws, size_t ws_size,
                              hipStream_t stream) {
    const float* feat    = (const float*)d_in[0];
    const int*   labels  = (const int*)d_in[1];
    const float* protos  = (const float*)d_in[2];
    const int*   plabels = (const int*)d_in[3];
    float* out = (float*)d_out;

    char* ws = (char*)d_ws;
    int*   count     = (int*)ws;                      // [0,16)       zeroed
    float* rowSumExp = (float*)(ws + 16);             // [16,32784)   zeroed
    float* rowSumS   = (float*)(ws + 16 + 32768);     // [...,65552)  zeroed
    float* Psum      = (float*)(ws + 65552);
    float* expPsum   = (float*)(ws + 98320);
    float* PLab      = (float*)(ws + 131088);
    int*   nf        = (int*)(ws + 163856);
    int*   perm      = (int*)(ws + 196624);
    float* diag      = (float*)(ws + 229392);
    unsigned short* Fb = (unsigned short*)(ws + 262160);            // 16B aligned
    unsigned short* Fn = (unsigned short*)(ws + 262160 + 2097152);  // 16B aligned

    hipMemsetAsync(d_ws, 0, 65552, stream);
    hipMemsetAsync(d_out, 0, sizeof(float), stream);

    k_proto2<<<M_TOT / 16, 256, 0, stream>>>(feat, labels, protos, plabels,
                                             Psum, expPsum, PLab, nf, perm, count, Fb, diag);
    k_gather<<<(M_TOT * 16) / 256, 256, 0, stream>>>(Fb, perm, count, Fn);
    dim3 gmain(M_TOT / CJ, M_TOT / 64);   // (16 chunks, 128 row-blocks); ~half exit early
    k_main<<<gmain, 256, 0, stream>>>(Fb, Fn, count, rowSumExp, rowSumS);
    k_final<<<M_TOT / 256, 256, 0, stream>>>(nf, rowSumExp, rowSumS,
                                             Psum, expPsum, PLab, diag, count, out);
}